// Round 1
// baseline (434.089 us; speedup 1.0000x reference)
//
#include <hip/hip_runtime.h>

// Classifier: out[40000][10] = (mean_J relu(x @ Wloc^T)) @ W^T
// x: [1200000][64] f32, Wloc: [128][64] f32, W: [10][128] f32.
//
// v2 strategy: M-dim = rows-within-segment (not segments). Each wave owns 16
// consecutive segments = one contiguous 123 KB slab of x. Per segment: two
// 16-row MFMA tiles (15 valid rows + 1 zero pad; pad rows give relu(0)=0 so
// pooling over all 16 C-rows is exact). Loads per tile are a contiguous
// ~3.8 KB window -> perfectly coalesced streaming. Distance-1-segment
// explicit prefetch hides HBM latency. Pool = per-lane rg-sum + shfl_xor
// cross-quad reduce.

typedef __bf16 bf16x8 __attribute__((ext_vector_type(8)));
typedef float f32x4 __attribute__((ext_vector_type(4)));

#define JJ 30
#define DIN 64
#define DENC 128
#define NCLS 10
#define SEG_PER_BLOCK 64   // 4 waves * 16 segments
#define FEATP 130          // padded leading dim for s_feats

union FragU { unsigned u[4]; bf16x8 v; };

// pack two f32 -> one dword of two bf16 (round-to-nearest via +0x8000, then
// v_perm_b32 grabs the high halves). hi lands in bits 31:16, lo in 15:0.
__device__ __forceinline__ unsigned pk_rn(float hi, float lo) {
  unsigned uh = __builtin_bit_cast(unsigned, hi) + 0x8000u;
  unsigned ul = __builtin_bit_cast(unsigned, lo) + 0x8000u;
  return __builtin_amdgcn_perm(uh, ul, 0x07060302u);
}

struct Tile { float4 a, b, c, d; };

// p already carries the per-lane offset (lrow*DIN + quad*8). Lanes with
// lrow==15 are the pad row: they load nothing and stay zero.
__device__ __forceinline__ void load_tile(const float* __restrict__ p, bool act, Tile& t) {
  if (act) {
    t.a = *(const float4*)p;
    t.b = *(const float4*)(p + 4);
    t.c = *(const float4*)(p + 32);
    t.d = *(const float4*)(p + 36);
  } else {
    t.a = make_float4(0.f, 0.f, 0.f, 0.f);
    t.b = make_float4(0.f, 0.f, 0.f, 0.f);
    t.c = make_float4(0.f, 0.f, 0.f, 0.f);
    t.d = make_float4(0.f, 0.f, 0.f, 0.f);
  }
}

// convert one 16-row tile to bf16 A-frags, run 16 MFMAs, relu+pool into part.
// C/D layout: row (tile row) = quad*4+rg, col = nt*16 + (lane&15).
__device__ __forceinline__ void accum_tile(const Tile& t, const FragU (&wb)[8][2],
                                           float (&part)[8]) {
  FragU a0, a1;
  a0.u[0] = pk_rn(t.a.y, t.a.x); a0.u[1] = pk_rn(t.a.w, t.a.z);
  a0.u[2] = pk_rn(t.b.y, t.b.x); a0.u[3] = pk_rn(t.b.w, t.b.z);
  a1.u[0] = pk_rn(t.c.y, t.c.x); a1.u[1] = pk_rn(t.c.w, t.c.z);
  a1.u[2] = pk_rn(t.d.y, t.d.x); a1.u[3] = pk_rn(t.d.w, t.d.z);
#pragma unroll
  for (int nt = 0; nt < 8; ++nt) {
    f32x4 z = {0.f, 0.f, 0.f, 0.f};
    f32x4 acc = __builtin_amdgcn_mfma_f32_16x16x32_bf16(a0.v, wb[nt][0].v, z, 0, 0, 0);
    acc = __builtin_amdgcn_mfma_f32_16x16x32_bf16(a1.v, wb[nt][1].v, acc, 0, 0, 0);
#pragma unroll
    for (int rg = 0; rg < 4; ++rg) part[nt] += fmaxf(acc[rg], 0.f);
  }
}

__global__ __launch_bounds__(256, 2)
void classifier_kernel(const float* __restrict__ x,
                       const float* __restrict__ wloc,
                       const float* __restrict__ w,
                       float* __restrict__ out) {
  __shared__ float s_feats[SEG_PER_BLOCK * FEATP]; // 33,280 B
  __shared__ float s_w[NCLS * DENC];               //  5,120 B

  const int tid  = threadIdx.x;
  const int wid  = tid >> 6;
  const int lane = tid & 63;
  const int quad = lane >> 4;
  const int lrow = lane & 15;

  // stage W into LDS (read after the single __syncthreads below)
  for (int i = tid; i < NCLS * DENC; i += 256) s_w[i] = w[i];

  // B fragments: whole Wloc in registers (unchanged, verified layout):
  // lane -> (n = lane&15, k = quad*8 + j); element =
  // Wloc[e = nt*16 + lrow][d = ks*32 + quad*8 + j], j consecutive.
  FragU wb[8][2];
#pragma unroll
  for (int nt = 0; nt < 8; ++nt) {
#pragma unroll
    for (int ks = 0; ks < 2; ++ks) {
      const float* p = wloc + (nt * 16 + lrow) * DIN + ks * 32 + quad * 8;
      float4 f0 = *(const float4*)p;
      float4 f1 = *(const float4*)(p + 4);
      wb[nt][ks].u[0] = pk_rn(f0.y, f0.x);
      wb[nt][ks].u[1] = pk_rn(f0.w, f0.z);
      wb[nt][ks].u[2] = pk_rn(f1.y, f1.x);
      wb[nt][ks].u[3] = pk_rn(f1.w, f1.z);
    }
  }

  const int seg0 = blockIdx.x * SEG_PER_BLOCK + wid * 16;
  const size_t srow = (size_t)seg0 * JJ;            // wave's first x-row
  const bool act = (lrow < 15);                     // lrow==15 is pad row
  // per-lane base: row lrow of a tile, k-offset quad*8
  const float* xl = x + (size_t)lrow * DIN + quad * 8;

  const float inv = 1.0f / 30.0f;

  Tile tA, tB, nA, nB;
  load_tile(xl + srow * DIN, act, tA);              // seg 0, rows 0..14
  load_tile(xl + (srow + 15) * DIN, act, tB);       // seg 0, rows 15..29

#pragma unroll 2
  for (int i = 0; i < 16; ++i) {
    // prefetch next segment's two tiles (distance-1-segment, ~7.7 KB/wave)
    if (i < 15) {
      size_t nrow = srow + (size_t)(i + 1) * JJ;
      load_tile(xl + nrow * DIN, act, nA);
      load_tile(xl + (nrow + 15) * DIN, act, nB);
    }

    float part[8] = {0.f, 0.f, 0.f, 0.f, 0.f, 0.f, 0.f, 0.f};
    accum_tile(tA, wb, part);
    accum_tile(tB, wb, part);

    // cross-quad reduce: lanes {lrow, lrow+16, lrow+32, lrow+48} hold the
    // 4 row-group partials of segment i; butterfly over bits 4,5.
#pragma unroll
    for (int nt = 0; nt < 8; ++nt) {
      float v = part[nt];
      v += __shfl_xor(v, 16);
      v += __shfl_xor(v, 32);
      if (quad == 0)
        s_feats[(wid * 16 + i) * FEATP + nt * 16 + lrow] = v * inv;
    }

    if (i < 15) { tA = nA; tB = nB; }
  }

  __syncthreads();

  // final tiny matmul: out[seg][c] = dot(feats[seg], W[c]) ; 640 outputs/block
  for (int i = tid; i < SEG_PER_BLOCK * NCLS; i += 256) {
    int sg = i / NCLS;
    int c  = i - sg * NCLS;
    const float* fr = s_feats + sg * FEATP;
    const float* wr = s_w + c * DENC;
    float acc = 0.f;
#pragma unroll 8
    for (int e = 0; e < DENC; ++e) acc += fr[e] * wr[e];
    out[(size_t)(blockIdx.x * SEG_PER_BLOCK + sg) * NCLS + c] = acc;
  }
}

extern "C" void kernel_launch(void* const* d_in, const int* in_sizes, int n_in,
                              void* d_out, int out_size, void* d_ws, size_t ws_size,
                              hipStream_t stream) {
  const float* x    = (const float*)d_in[0];
  const float* wloc = (const float*)d_in[1];
  const float* w    = (const float*)d_in[2];
  float* out = (float*)d_out;
  // 40000 segments / 64 per block = 625 blocks exactly
  classifier_kernel<<<dim3(625), dim3(256), 0, stream>>>(x, wloc, w, out);
}